// Round 10
// baseline (137.110 us; speedup 1.0000x reference)
//
#include <hip/hip_runtime.h>
#include <hip/hip_bf16.h>
#include <math.h>

// Problem constants
#define BQ   4096
#define D    256
#define NH   8
#define HD   32
#define LN_  64     // neighbors per node
#define DFF  1024
#define EPSV 1e-5f
#define QSCALE 0.17677669529663687f  // HD^-0.5

typedef __attribute__((ext_vector_type(8))) short short8;
typedef __attribute__((ext_vector_type(4))) float f32x4;

// LDS XOR swizzle (G4): spread 512B/256B/128B-stride rows across banks; bijective involution.
#define ESWZ(row, byte) ((byte) ^ (((row) & 7) << 4))

// ---------------- helpers ----------------
__device__ __forceinline__ float wave_sum(float v){
#pragma unroll
  for (int off = 32; off; off >>= 1) v += __shfl_xor(v, off, 64);
  return v;
}
// native converts -> compiler emits v_cvt_pk_bf16_f32 (1 inst per pair)
__device__ __forceinline__ unsigned short f2bf(float f){
  __hip_bfloat16 h = __float2bfloat16(f);
  unsigned short r; __builtin_memcpy(&r, &h, 2); return r;
}
__device__ __forceinline__ unsigned pk2(float a, float b){
  __hip_bfloat162 h = __float22bfloat162_rn(make_float2(a, b));
  unsigned r; __builtin_memcpy(&r, &h, 4); return r;
}
__device__ __forceinline__ float bflo(unsigned u){ return __uint_as_float(u << 16); }
__device__ __forceinline__ float bfhi(unsigned u){ return __uint_as_float(u & 0xFFFF0000u); }

// ---------------- prep kernel (weights + detect only; gather moved to k_pg) ----------------
// blocks 0-63  : W1 -> W1t bf16 [1024][256]
// blocks 64-127: W2 -> W2t bf16 [256][1024]
// blocks 128-255: Mt bf16 [2048][256] = QSCALE * Wk x Wq fold; + pb
// blocks 256-383: Gt bf16 [256][2048] = Wv x Wo fold
// block  384   : bo2 = bo + bv@Wo
// blocks 385-640: mask dtype detect -> flagsArr
__global__ __launch_bounds__(256) void k_prep(
    const float* __restrict__ Wq, const float* __restrict__ Wk,
    const float* __restrict__ Wv, const float* __restrict__ Wo,
    const float* __restrict__ W1, const float* __restrict__ W2,
    const float* __restrict__ bq, const float* __restrict__ bv,
    const float* __restrict__ bo,
    const unsigned int* __restrict__ maskw,
    unsigned short* __restrict__ W1t, unsigned short* __restrict__ W2t,
    unsigned short* __restrict__ Mt, unsigned short* __restrict__ Gt,
    float* __restrict__ pb, float* __restrict__ bo2,
    int* __restrict__ flagsArr){
  __shared__ float smem[4224];
  const int bid = blockIdx.x;
  const int tid = threadIdx.x;

  if (bid < 128){
    const float* src; unsigned short* dst; int K, N, t0;
    if (bid < 64){ src = W1; dst = W1t; K = 256;  N = 1024; t0 = bid; }
    else         { src = W2; dst = W2t; K = 1024; N = 256;  t0 = bid - 64; }
    const int ntx = N / 64;
    const int k0 = (t0 / ntx) * 64, n0 = (t0 % ntx) * 64;
    float (*Ts)[65] = (float(*)[65])smem;
    {
      int r = tid >> 2, c4 = (tid & 3) * 16;
#pragma unroll
      for (int i = 0; i < 4; i++)
        *(float4*)&Ts[r][c4 + i * 4] = *(const float4*)(src + (size_t)(k0 + r) * N + n0 + c4 + i * 4);
    }
    __syncthreads();
    {
      int n = tid >> 2, kc = (tid & 3) * 16;
      unsigned int pk[8];
#pragma unroll
      for (int i = 0; i < 8; i++)
        pk[i] = pk2(Ts[kc + 2 * i][n], Ts[kc + 2 * i + 1][n]);
      unsigned short* orow = dst + (size_t)(n0 + n) * K + k0 + kc;
      *(uint4*)(orow)     = *(uint4*)&pk[0];
      *(uint4*)(orow + 8) = *(uint4*)&pk[4];
    }
    return;
  }
  if (bid < 256){
    int t0 = bid - 128;
    int hd0 = (t0 & 31) * 64, c0 = (t0 >> 5) * 64;
    int h = hd0 >> 8, d0 = hd0 & 255;
    float (*WqS)[33] = (float(*)[33])smem;
    float (*WkS)[33] = (float(*)[33])(smem + 64 * 33);
#pragma unroll
    for (int s = 0; s < 2; s++){
      int idx = tid + s * 256;
      int row = idx >> 3, c4 = (idx & 7) * 4;
      *(float4*)&WqS[row][c4] = *(const float4*)(Wq + (size_t)(c0 + row) * 256 + h * 32 + c4);
      *(float4*)&WkS[row][c4] = *(const float4*)(Wk + (size_t)(d0 + row) * 256 + h * 32 + c4);
    }
    __syncthreads();
    int jo = (tid >> 4) * 4, io = (tid & 15) * 4;
    float acc[4][4];
#pragma unroll
    for (int j = 0; j < 4; j++)
#pragma unroll
      for (int i = 0; i < 4; i++) acc[j][i] = 0.f;
#pragma unroll
    for (int t = 0; t < 32; t++){
#pragma unroll
      for (int j = 0; j < 4; j++){
        float kv = WkS[jo + j][t];
#pragma unroll
        for (int i = 0; i < 4; i++) acc[j][i] = fmaf(kv, WqS[io + i][t], acc[j][i]);
      }
    }
#pragma unroll
    for (int j = 0; j < 4; j++){
      uint2 o;
      o.x = pk2(acc[j][0] * QSCALE, acc[j][1] * QSCALE);
      o.y = pk2(acc[j][2] * QSCALE, acc[j][3] * QSCALE);
      *(uint2*)(Mt + (size_t)(hd0 + jo + j) * 256 + c0 + io) = o;
    }
    if (c0 == 0 && tid < 64){
      float s = 0.f;
#pragma unroll
      for (int t = 0; t < 32; t++) s = fmaf(WkS[tid][t], bq[h * 32 + t], s);
      pb[hd0 + tid] = s * QSCALE;
    }
    return;
  }
  if (bid < 384){
    int t0 = bid - 256;
    int hd0 = (t0 & 31) * 64, n0 = (t0 >> 5) * 64;
    int h = hd0 >> 8, d0 = hd0 & 255;
    float (*WvS)[33] = (float(*)[33])smem;
    float (*WoS)[65] = (float(*)[65])(smem + 64 * 33);
#pragma unroll
    for (int s = 0; s < 2; s++){
      int idx = tid + s * 256;
      int row = idx >> 3, c4 = (idx & 7) * 4;
      *(float4*)&WvS[row][c4] = *(const float4*)(Wv + (size_t)(d0 + row) * 256 + h * 32 + c4);
      int row2 = idx >> 4, c42 = (idx & 15) * 4;
      *(float4*)&WoS[row2][c42] = *(const float4*)(Wo + (size_t)(h * 32 + row2) * 256 + n0 + c42);
    }
    __syncthreads();
    int jo = (tid >> 4) * 4, io = (tid & 15) * 4;
    float acc[4][4];
#pragma unroll
    for (int i = 0; i < 4; i++)
#pragma unroll
      for (int j = 0; j < 4; j++) acc[i][j] = 0.f;
#pragma unroll
    for (int t = 0; t < 32; t++){
#pragma unroll
      for (int i = 0; i < 4; i++){
        float ov = WoS[t][io + i];
#pragma unroll
        for (int j = 0; j < 4; j++) acc[i][j] = fmaf(ov, WvS[jo + j][t], acc[i][j]);
      }
    }
#pragma unroll
    for (int i = 0; i < 4; i++){
      uint2 o;
      o.x = pk2(acc[i][0], acc[i][1]);
      o.y = pk2(acc[i][2], acc[i][3]);
      *(uint2*)(Gt + (size_t)(n0 + io + i) * 2048 + hd0 + jo) = o;
    }
    return;
  }
  if (bid == 384){
    int n = tid;
    float s = bo[n];
    for (int j = 0; j < 256; j++) s = fmaf(bv[j], Wo[(size_t)j * 256 + n], s);
    bo2[n] = s;
    return;
  }
  {
    int* df = (int*)smem;
    if (tid == 0) df[0] = 0;
    __syncthreads();
    int idx = (bid - 385) * 256 + tid;
    unsigned int v = maskw[idx];
    int bits = 0;
    if (v == 0x3F800000u) bits = 2;
    else if (v & 0xFFFFFF00u) bits = 1;
    int b2 = __any(bits & 2) ? 2 : 0;
    int b1 = __any(bits & 1) ? 1 : 0;
    if ((tid & 63) == 0 && (b1 | b2)) atomicOr(df, b1 | b2);
    __syncthreads();
    if (tid == 0) flagsArr[bid - 385] = df[0];
  }
}

// ---------------- P-GEMM with fused gather: P = emb[batch] @ Mt^T + pb (bf16 out) ----------------
// BM=128, BN=64, K=256. A staged by gathering f32 emb rows and packing to bf16 inline.
__global__ __launch_bounds__(256) void k_pg(const int* __restrict__ batch,
                                            const float* __restrict__ emb,
                                            const unsigned short* __restrict__ Bt,   // Mt
                                            const float* __restrict__ bias,          // pb
                                            unsigned short* __restrict__ Cout){
  constexpr int BM = 128, BN = 64, BK = 64, K = 256, N = 2048;
  constexpr int WM = 64, WN = 32, MR = 4, NR = 2;
  __shared__ __align__(16) unsigned short As[BM * BK];
  __shared__ __align__(16) unsigned short Bs[BN * BK];
  char* ab = (char*)As; char* bb = (char*)Bs;
  const int tid = threadIdx.x;
  const int w = tid >> 6, lane = tid & 63;
  const int wm = w >> 1, wn = w & 1;
  const int gx = gridDim.x;
  const int nwg = gx * gridDim.y;
  const int o = blockIdx.y * gx + blockIdx.x;
  const int lin = (o & 7) * (nwg >> 3) + (o >> 3);
  const int row0 = (lin / gx) * BM, col0 = (lin % gx) * BN;
  f32x4 acc[MR][NR];
#pragma unroll
  for (int m = 0; m < MR; m++)
#pragma unroll
    for (int n = 0; n < NR; n++) acc[m][n] = (f32x4){0.f, 0.f, 0.f, 0.f};

  for (int k0 = 0; k0 < K; k0 += BK){
#pragma unroll
    for (int s = 0; s < 4; s++){            // A: gather f32 -> bf16
      int c = s * 256 + tid;
      int r = c >> 3, jj = c & 7;
      const float* src = emb + (size_t)batch[row0 + r] * D + k0 + jj * 8;
      float4 v0 = *(const float4*)(src);
      float4 v1 = *(const float4*)(src + 4);
      uint4 pk;
      pk.x = pk2(v0.x, v0.y); pk.y = pk2(v0.z, v0.w);
      pk.z = pk2(v1.x, v1.y); pk.w = pk2(v1.z, v1.w);
      *(uint4*)(ab + ESWZ(r, r * 128 + jj * 16)) = pk;
    }
#pragma unroll
    for (int s = 0; s < 2; s++){            // B: Mt bf16
      int c = s * 256 + tid;
      int r = c >> 3, jj = c & 7;
      uint4 v = *(const uint4*)(Bt + (size_t)(col0 + r) * K + k0 + jj * 8);
      *(uint4*)(bb + ESWZ(r, r * 128 + jj * 16)) = v;
    }
    __syncthreads();
#pragma unroll
    for (int kk = 0; kk < 2; kk++){
      short8 af[MR], bf[NR];
#pragma unroll
      for (int m = 0; m < MR; m++){
        int r = wm * WM + m * 16 + (lane & 15);
        af[m] = *(const short8*)(ab + ESWZ(r, r * 128 + (kk * 4 + (lane >> 4)) * 16));
      }
#pragma unroll
      for (int n = 0; n < NR; n++){
        int r = wn * WN + n * 16 + (lane & 15);
        bf[n] = *(const short8*)(bb + ESWZ(r, r * 128 + (kk * 4 + (lane >> 4)) * 16));
      }
#pragma unroll
      for (int m = 0; m < MR; m++)
#pragma unroll
        for (int n = 0; n < NR; n++)
          acc[m][n] = __builtin_amdgcn_mfma_f32_16x16x32_bf16(af[m], bf[n], acc[m][n], 0, 0, 0);
    }
    __syncthreads();
  }
#pragma unroll
  for (int m = 0; m < MR; m++){
#pragma unroll
    for (int n = 0; n < NR; n++){
      int col = col0 + wn * WN + n * 16 + (lane & 15);
      float bsv = bias[col];
      int rbase = row0 + wm * WM + m * 16 + (lane >> 4) * 4;
#pragma unroll
      for (int r = 0; r < 4; r++)
        Cout[(size_t)(rbase + r) * N + col] = f2bf(acc[m][n][r] + bsv);
    }
  }
}

// ---------------- bf16 MFMA GEMM (direct staging) + XCD swizzle (FFN1) ----------------
template<int BM, int BN, int EPI, bool OUTBF>
__global__ __launch_bounds__(256) void k_mgemm(const unsigned short* __restrict__ A,
                                               const unsigned short* __restrict__ Bt,
                                               const float* __restrict__ bias,
                                               void* __restrict__ Cout,
                                               int M, int N, int K){
  constexpr int BK = 64;
  constexpr int WM = BM / 2, WN = BN / 2;
  constexpr int MR = WM / 16, NR = WN / 16;
  constexpr int AIT = BM * 8 / 256;
  constexpr int BIT = BN * 8 / 256;
  __shared__ __align__(16) unsigned short As[BM * BK];
  __shared__ __align__(16) unsigned short Bs[BN * BK];
  char* ab = (char*)As; char* bb = (char*)Bs;
  const int tid = threadIdx.x;
  const int w = tid >> 6, lane = tid & 63;
  const int wm = w >> 1, wn = w & 1;
  const int gx = gridDim.x;
  const int nwg = gx * gridDim.y;
  const int o = blockIdx.y * gx + blockIdx.x;
  const int lin = (o & 7) * (nwg >> 3) + (o >> 3);
  const int row0 = (lin / gx) * BM, col0 = (lin % gx) * BN;
  f32x4 acc[MR][NR];
#pragma unroll
  for (int m = 0; m < MR; m++)
#pragma unroll
    for (int n = 0; n < NR; n++) acc[m][n] = (f32x4){0.f, 0.f, 0.f, 0.f};

  for (int k0 = 0; k0 < K; k0 += BK){
#pragma unroll
    for (int s = 0; s < AIT; s++){
      int c = s * 256 + tid;
      int r = c >> 3, jj = c & 7;
      uint4 v = *(const uint4*)(A + (size_t)(row0 + r) * K + k0 + jj * 8);
      *(uint4*)(ab + ESWZ(r, r * 128 + jj * 16)) = v;
    }
#pragma unroll
    for (int s = 0; s < BIT; s++){
      int c = s * 256 + tid;
      int r = c >> 3, jj = c & 7;
      uint4 v = *(const uint4*)(Bt + (size_t)(col0 + r) * K + k0 + jj * 8);
      *(uint4*)(bb + ESWZ(r, r * 128 + jj * 16)) = v;
    }
    __syncthreads();
#pragma unroll
    for (int kk = 0; kk < 2; kk++){
      short8 af[MR], bf[NR];
#pragma unroll
      for (int m = 0; m < MR; m++){
        int r = wm * WM + m * 16 + (lane & 15);
        af[m] = *(const short8*)(ab + ESWZ(r, r * 128 + (kk * 4 + (lane >> 4)) * 16));
      }
#pragma unroll
      for (int n = 0; n < NR; n++){
        int r = wn * WN + n * 16 + (lane & 15);
        bf[n] = *(const short8*)(bb + ESWZ(r, r * 128 + (kk * 4 + (lane >> 4)) * 16));
      }
#pragma unroll
      for (int m = 0; m < MR; m++)
#pragma unroll
        for (int n = 0; n < NR; n++)
          acc[m][n] = __builtin_amdgcn_mfma_f32_16x16x32_bf16(af[m], bf[n], acc[m][n], 0, 0, 0);
    }
    __syncthreads();
  }
#pragma unroll
  for (int m = 0; m < MR; m++){
#pragma unroll
    for (int n = 0; n < NR; n++){
      int col = col0 + wn * WN + n * 16 + (lane & 15);
      float bsv = bias[col];
      int rbase = row0 + wm * WM + m * 16 + (lane >> 4) * 4;
#pragma unroll
      for (int r = 0; r < 4; r++){
        float v = acc[m][n][r] + bsv;
        if (EPI == 3) v = fmaxf(v, 0.f);
        if (OUTBF) ((unsigned short*)Cout)[(size_t)(rbase + r) * N + col] = f2bf(v);
        else       ((float*)Cout)[(size_t)(rbase + r) * N + col] = v;
      }
    }
  }
}

// ---------------- fused GEMM + residual + LayerNorm ----------------
// outF(,outB) = LN( resid + epi(A[16-tile] @ Bt[256xK]^T + bias) )
// RELU: relu before residual. GX: resid = emb[batch[row]] gather, else resid = residP.
// 16 rows x full 256 cols per block; 4 waves cols w*64. Bs reused as f32 [16][257] for LN.
template<bool RELU, bool GX, bool WBF>
__global__ __launch_bounds__(256) void k_gln(const unsigned short* __restrict__ A,
                                             const unsigned short* __restrict__ Bt,
                                             const float* __restrict__ bias,
                                             const int* __restrict__ batch,
                                             const float* __restrict__ emb,
                                             const float* __restrict__ residP,
                                             const float* __restrict__ lnw,
                                             const float* __restrict__ lnb,
                                             float* __restrict__ outF,
                                             unsigned short* __restrict__ outB,
                                             int K){
  constexpr int NR = 4;
  __shared__ __align__(16) unsigned short As[16 * 64];    // 2 KB
  __shared__ __align__(16) unsigned short Bs[256 * 64];   // 32 KB; reused as f32 LN buffer
  char* ab = (char*)As; char* bb = (char*)Bs;
  const int tid = threadIdx.x;
  const int w = tid >> 6, lane = tid & 63;
  const int row0 = blockIdx.x * 16;
  f32x4 acc[NR];
#pragma unroll
  for (int n = 0; n < NR; n++) acc[n] = (f32x4){0.f, 0.f, 0.f, 0.f};

  for (int k0 = 0; k0 < K; k0 += 64){
    if (tid < 128){                          // A: 16x64 = 128 uint4
      int r = tid >> 3, jj = tid & 7;
      uint4 v = *(const uint4*)(A + (size_t)(row0 + r) * K + k0 + jj * 8);
      *(uint4*)(ab + ESWZ(r, r * 128 + jj * 16)) = v;
    }
#pragma unroll
    for (int s = 0; s < 8; s++){             // B: 256x64 = 2048 uint4
      int c = s * 256 + tid;
      int r = c >> 3, jj = c & 7;
      uint4 v = *(const uint4*)(Bt + (size_t)r * K + k0 + jj * 8);
      *(uint4*)(bb + ESWZ(r, r * 128 + jj * 16)) = v;
    }
    __syncthreads();
#pragma unroll
    for (int kk = 0; kk < 2; kk++){
      int r = lane & 15;
      short8 af = *(const short8*)(ab + ESWZ(r, r * 128 + (kk * 4 + (lane >> 4)) * 16));
#pragma unroll
      for (int n = 0; n < NR; n++){
        int rb = w * 64 + n * 16 + (lane & 15);
        short8 bf = *(const short8*)(bb + ESWZ(rb, rb * 128 + (kk * 4 + (lane >> 4)) * 16));
        acc[n] = __builtin_amdgcn_mfma_f32_16x16x32_bf16(af, bf, acc[n], 0, 0, 0);
      }
    }
    __syncthreads();
  }
  // dump acc + bias (+relu) + residual into f32 LDS [16][257]
  float* sf = (float*)Bs;
#pragma unroll
  for (int n = 0; n < NR; n++){
    int col = w * 64 + n * 16 + (lane & 15);
    float bsv = bias[col];
#pragma unroll
    for (int r = 0; r < 4; r++){
      int row = (lane >> 4) * 4 + r;
      float v = acc[n][r] + bsv;
      if (RELU) v = fmaxf(v, 0.f);
      float rv;
      if (GX) rv = emb[(size_t)batch[row0 + row] * D + col];
      else    rv = residP[(size_t)(row0 + row) * D + col];
      sf[row * 257 + col] = v + rv;
    }
  }
  __syncthreads();
  // LN: thread t -> row t>>4, segment (t&15)*16..+15; 16-lane shfl reduce
  {
    int row = tid >> 4, seg = tid & 15;
    float vals[16];
    float s = 0.f, s2 = 0.f;
#pragma unroll
    for (int j = 0; j < 16; j++){
      float v = sf[row * 257 + seg * 16 + j];
      vals[j] = v; s += v; s2 += v * v;
    }
#pragma unroll
    for (int off = 8; off; off >>= 1){
      s += __shfl_xor(s, off, 64);
      s2 += __shfl_xor(s2, off, 64);
    }
    float mu = s * (1.f / 256.f);
    float var = s2 * (1.f / 256.f) - mu * mu;
    float rstd = rsqrtf(var + EPSV);
#pragma unroll
    for (int j = 0; j < 16; j++){
      int col = seg * 16 + j;
      float res = (vals[j] - mu) * rstd * lnw[col] + lnb[col];
      outF[(size_t)(row0 + row) * D + col] = res;
      if (WBF) outB[(size_t)(row0 + row) * D + col] = f2bf(res);
    }
  }
}

// ---------------- attention core (r9 structure, unchanged — at gather-BW ceiling) ----------------
__global__ __launch_bounds__(256) void k_attn(const int* __restrict__ nei_idx,
                                              const void* __restrict__ nei_mask,
                                              const int* __restrict__ flagsArr,
                                              const float* __restrict__ emb,
                                              const unsigned short* __restrict__ Pb,
                                              unsigned short* __restrict__ Cb){
  const int b = blockIdx.x;
  const int tid = threadIdx.x;
  const int w = tid >> 6, lane = tid & 63;
  __shared__ __align__(16) unsigned short EbfH[64 * 128]; // 16 KB: E k-half tile / PV partials
  __shared__ __align__(16) unsigned short Pl[9 * 256];    // 4.5 KB, row 8 = zeros
  __shared__ float sc[NH * LN_];
  __shared__ float mskv[LN_];
  __shared__ int   fred[4];
  char* eb = (char*)EbfH;
  char* pl = (char*)Pl;
  unsigned* pfu = (unsigned*)EbfH;

  {
    int f = flagsArr[tid];
#pragma unroll
    for (int off = 32; off; off >>= 1) f |= __shfl_xor(f, off, 64);
    if (lane == 0) fred[w] = f;
  }
  float4 vr[16];
#pragma unroll
  for (int i = 0; i < 16; i++){
    int nid = nei_idx[(size_t)b * LN_ + w * 16 + i];
    vr[i] = ((const float4*)(emb + (size_t)nid * D))[lane];
  }
  {
    int r = tid >> 5, cb16 = (tid & 31) * 16;
    uint4 v = *(const uint4*)((const char*)Pb + (size_t)b * 4096 + r * 512 + cb16);
    *(uint4*)(pl + ESWZ(r, r * 512 + cb16)) = v;
  }
  if (tid < 64) *(uint2*)(pl + 8 * 512 + tid * 8) = make_uint2(0u, 0u);
  __syncthreads();

  if (tid < LN_){
    int fl = fred[0] | fred[1] | fred[2] | fred[3];
    int mf = (fl & 2) ? 2 : ((fl & 1) ? 1 : 0);
    bool m;
    if (mf == 1)      m = ((const unsigned char*)nei_mask)[(size_t)b * LN_ + tid] != 0;
    else if (mf == 2) m = ((const float*)nei_mask)[(size_t)b * LN_ + tid] != 0.f;
    else              m = ((const int*)nei_mask)[(size_t)b * LN_ + tid] != 0;
    mskv[tid] = m ? 1.f : 0.f;
  }

  f32x4 acc = {0.f, 0.f, 0.f, 0.f};
  const int hr = lane & 15;
  const int arow = hr < 8 ? hr : 8;
  const int bl = w * 16 + (lane & 15);
  const int koff = (lane >> 4) * 16;
#pragma unroll
  for (int half = 0; half < 2; half++){
    if ((lane >> 5) == half){
      int cl = lane & 31;
#pragma unroll
      for (int i = 0; i < 16; i++){
        int l = w * 16 + i;
        uint2 p;
        p.x = pk2(vr[i].x, vr[i].y);
        p.y = pk2(vr[i].z, vr[i].w);
        *(uint2*)(eb + ESWZ(l, l * 256 + cl * 8)) = p;
      }
    }
    __syncthreads();
    __builtin_amdgcn_s_setprio(1);
#pragma unroll
    for (int kk = 0; kk < 4; kk++){
      int kabs = half * 4 + kk;
      short8 af = *(const short8*)(pl + ESWZ(arow, arow * 512 + kabs * 64 + koff));
      short8 bf = *(const short8*)(eb + ESWZ(bl, bl * 256 + kk * 64 + koff));
      acc = __builtin_amdgcn_mfma_f32_16x16x32_bf16(af, bf, acc, 0, 0, 0);
    }
    __builtin_amdgcn_s_setprio(0);
    __syncthreads();
  }
  {
    int hb = (lane >> 4) * 4;
    if (hb < 8){
#pragma unroll
      for (int r = 0; r < 4; r++) sc[(hb + r) * LN_ + bl] = acc[r];
    }
  }
  __syncthreads();

  {
    int h = tid >> 5, j = tid & 31;
    float v0 = mskv[j]      > 0.5f ? -INFINITY : sc[h * LN_ + j];
    float v1 = mskv[j + 32] > 0.5f ? -INFINITY : sc[h * LN_ + j + 32];
    float m = fmaxf(v0, v1);
#pragma unroll
    for (int off = 16; off; off >>= 1) m = fmaxf(m, __shfl_xor(m, off, 64));
    float e0 = __expf(v0 - m), e1 = __expf(v1 - m);
    float s = e0 + e1;
#pragma unroll
    for (int off = 16; off; off >>= 1) s += __shfl_xor(s, off, 64);
    float inv = 1.f / s;
    sc[h * LN_ + j]      = e0 * inv;
    sc[h * LN_ + j + 32] = e1 * inv;
  }
  __syncthreads();

  {
    float4 pacc[NH];
#pragma unroll
    for (int h = 0; h < NH; h++) pacc[h] = make_float4(0.f, 0.f, 0.f, 0.f);
#pragma unroll
    for (int i = 0; i < 16; i++){
      int l = w * 16 + i;
#pragma unroll
      for (int h = 0; h < NH; h++){
        float t = sc[h * LN_ + l];
        pacc[h].x = fmaf(t, vr[i].x, pacc[h].x);
        pacc[h].y = fmaf(t, vr[i].y, pacc[h].y);
        pacc[h].z = fmaf(t, vr[i].z, pacc[h].z);
        pacc[h].w = fmaf(t, vr[i].w, pacc[h].w);
      }
    }
#pragma unroll
    for (int h = 0; h < NH; h++){
      uint2 p;
      p.x = pk2(pacc[h].x, pacc[h].y);
      p.y = pk2(pacc[h].z, pacc[h].w);
      *(uint2*)&pfu[w * 1024 + h * 128 + lane * 2] = p;
    }
  }
  __syncthreads();

#pragma unroll
  for (int s = 0; s < 2; s++){
    int gi = tid + s * 256;
    int h = gi >> 6, d4 = gi & 63;
    float x = 0.f, y = 0.f, z = 0.f, u = 0.f;
#pragma unroll
    for (int wv = 0; wv < 4; wv++){
      uint2 p = *(uint2*)&pfu[wv * 1024 + h * 128 + d4 * 2];
      x += bflo(p.x); y += bfhi(p.x);
      z += bflo(p.y); u += bfhi(p.y);
    }
    uint2 o;
    o.x = pk2(x, y);
    o.y = pk2(z, u);
    *(uint2*)(Cb + (size_t)b * 2048 + h * 256 + d4 * 4) = o;
  }
}

// ---------------- launch ----------------
extern "C" void kernel_launch(void* const* d_in, const int* in_sizes, int n_in,
                              void* d_out, int out_size, void* d_ws, size_t ws_size,
                              hipStream_t stream){
  (void)in_sizes; (void)n_in; (void)out_size; (void)ws_size;
  const int*   batch    = (const int*)d_in[0];
  const int*   nei_idx  = (const int*)d_in[1];
  const void*  nei_mask = d_in[2];
  const float* emb      = (const float*)d_in[3];
  const float* Wq = (const float*)d_in[4];  const float* bq = (const float*)d_in[5];
  const float* Wk = (const float*)d_in[6];  /* bk dropped: softmax-invariant */
  const float* Wv = (const float*)d_in[8];  const float* bv = (const float*)d_in[9];
  const float* Wo = (const float*)d_in[10]; const float* bo = (const float*)d_in[11];
  const float* W1 = (const float*)d_in[12]; const float* b1 = (const float*)d_in[13];
  const float* W2 = (const float*)d_in[14]; const float* b2 = (const float*)d_in[15];
  const float* ln1w = (const float*)d_in[16]; const float* ln1b = (const float*)d_in[17];
  const float* ln2w = (const float*)d_in[18]; const float* ln2b = (const float*)d_in[19];

  float* ws = (float*)d_ws;
  // 4-MiB slots
  float* S  = ws + (size_t)2 * 1048576;  // slot 2
  unsigned short* Pbf = (unsigned short*)(ws + (size_t)4 * 1048576);  // slots 4-7 [4096][2048]
  unsigned short* Cb  = Pbf;             // alias: attn block b reads P[b] fully before writing C[b]
  unsigned short* Sb  = (unsigned short*)(ws + (size_t)8 * 1048576);  // slot 8
  unsigned short* HHb = (unsigned short*)(ws + (size_t)9 * 1048576);  // slots 9-10
  char* wb = (char*)(ws + (size_t)12 * 1048576);
  unsigned short* W1t = (unsigned short*)(wb);                        // 512 KiB
  unsigned short* W2t = (unsigned short*)(wb + (512u << 10));         // 512 KiB
  unsigned short* Mt  = (unsigned short*)(wb + (1024u << 10));        // 1 MiB
  unsigned short* Gt  = (unsigned short*)(wb + (2048u << 10));        // 1 MiB
  float* pbv  = (float*)(wb + (3072u << 10));                         // 8 KiB
  float* bo2  = (float*)(wb + (3072u << 10) + 8192);                  // 1 KiB
  int*   flagsArr = (int*)(wb + (3072u << 10) + 16384);               // 256 ints
  float* out = (float*)d_out;

  k_prep<<<641, 256, 0, stream>>>(Wq, Wk, Wv, Wo, W1, W2, bq, bv, bo,
                                  (const unsigned int*)nei_mask,
                                  W1t, W2t, Mt, Gt, pbv, bo2, flagsArr);
  // P = gather(emb,batch) @ Mt^T + pb  [bf16]
  k_pg<<<dim3(2048 / 64, BQ / 128), 256, 0, stream>>>(batch, emb, Mt, pbv, Pbf);
  k_attn<<<BQ, 256, 0, stream>>>(nei_idx, nei_mask, flagsArr, emb, Pbf, Cb);
  // S,Sb = LN1( gather(emb,batch) + Cb @ Gt^T + bo2 )
  k_gln<false, true, true><<<BQ / 16, 256, 0, stream>>>(Cb, Gt, bo2, batch, emb, nullptr,
                                                        ln1w, ln1b, S, Sb, 2048);
  // HH = relu(Sb @ W1t + b1)  [bf16]
  k_mgemm<128, 64, 3, true><<<dim3(DFF / 64, BQ / 128), 256, 0, stream>>>(Sb, W1t, b1, HHb, BQ, DFF, 256);
  // out = LN2( S + relu(HHb @ W2t + b2) )
  k_gln<true, false, false><<<BQ / 16, 256, 0, stream>>>(HHb, W2t, b2, nullptr, nullptr, S,
                                                         ln2w, ln2b, out, nullptr, 1024);
}

// Round 11
// 119.653 us; speedup vs baseline: 1.1459x; 1.1459x over previous
//
#include <hip/hip_runtime.h>
#include <hip/hip_bf16.h>
#include <math.h>

// Problem constants
#define BQ   4096
#define D    256
#define NH   8
#define HD   32
#define LN_  64     // neighbors per node
#define DFF  1024
#define EPSV 1e-5f
#define QSCALE 0.17677669529663687f  // HD^-0.5

typedef __attribute__((ext_vector_type(8))) short short8;
typedef __attribute__((ext_vector_type(4))) float f32x4;

// LDS XOR swizzle (G4): spread 512B/256B/128B-stride rows across banks; bijective involution.
#define ESWZ(row, byte) ((byte) ^ (((row) & 7) << 4))

// ---------------- helpers ----------------
__device__ __forceinline__ float wave_sum(float v){
#pragma unroll
  for (int off = 32; off; off >>= 1) v += __shfl_xor(v, off, 64);
  return v;
}
// native converts -> compiler emits v_cvt_pk_bf16_f32 (1 inst per pair)
__device__ __forceinline__ unsigned short f2bf(float f){
  __hip_bfloat16 h = __float2bfloat16(f);
  unsigned short r; __builtin_memcpy(&r, &h, 2); return r;
}
__device__ __forceinline__ unsigned pk2(float a, float b){
  __hip_bfloat162 h = __float22bfloat162_rn(make_float2(a, b));
  unsigned r; __builtin_memcpy(&r, &h, 4); return r;
}
__device__ __forceinline__ float bflo(unsigned u){ return __uint_as_float(u << 16); }
__device__ __forceinline__ float bfhi(unsigned u){ return __uint_as_float(u & 0xFFFF0000u); }

// ---------------- mega-prep kernel (block-range dispatch) ----------------
__global__ __launch_bounds__(256) void k_prep(
    const float* __restrict__ Wq, const float* __restrict__ Wk,
    const float* __restrict__ Wv, const float* __restrict__ Wo,
    const float* __restrict__ W1, const float* __restrict__ W2,
    const float* __restrict__ bq, const float* __restrict__ bv,
    const float* __restrict__ bo,
    const int* __restrict__ batch, const float* __restrict__ emb,
    const unsigned int* __restrict__ maskw,
    unsigned short* __restrict__ W1t, unsigned short* __restrict__ W2t,
    unsigned short* __restrict__ Mt, unsigned short* __restrict__ Gt,
    float* __restrict__ pb, float* __restrict__ bo2,
    float* __restrict__ X, unsigned short* __restrict__ Xb,
    int* __restrict__ flagsArr){
  __shared__ float smem[4224];
  const int bid = blockIdx.x;
  const int tid = threadIdx.x;

  if (bid < 128){
    const float* src; unsigned short* dst; int K, N, t0;
    if (bid < 64){ src = W1; dst = W1t; K = 256;  N = 1024; t0 = bid; }
    else         { src = W2; dst = W2t; K = 1024; N = 256;  t0 = bid - 64; }
    const int ntx = N / 64;
    const int k0 = (t0 / ntx) * 64, n0 = (t0 % ntx) * 64;
    float (*Ts)[65] = (float(*)[65])smem;
    {
      int r = tid >> 2, c4 = (tid & 3) * 16;
#pragma unroll
      for (int i = 0; i < 4; i++)
        *(float4*)&Ts[r][c4 + i * 4] = *(const float4*)(src + (size_t)(k0 + r) * N + n0 + c4 + i * 4);
    }
    __syncthreads();
    {
      int n = tid >> 2, kc = (tid & 3) * 16;
      unsigned int pk[8];
#pragma unroll
      for (int i = 0; i < 8; i++)
        pk[i] = pk2(Ts[kc + 2 * i][n], Ts[kc + 2 * i + 1][n]);
      unsigned short* orow = dst + (size_t)(n0 + n) * K + k0 + kc;
      *(uint4*)(orow)     = *(uint4*)&pk[0];
      *(uint4*)(orow + 8) = *(uint4*)&pk[4];
    }
    return;
  }
  if (bid < 256){
    int t0 = bid - 128;
    int hd0 = (t0 & 31) * 64, c0 = (t0 >> 5) * 64;
    int h = hd0 >> 8, d0 = hd0 & 255;
    float (*WqS)[33] = (float(*)[33])smem;
    float (*WkS)[33] = (float(*)[33])(smem + 64 * 33);
#pragma unroll
    for (int s = 0; s < 2; s++){
      int idx = tid + s * 256;
      int row = idx >> 3, c4 = (idx & 7) * 4;
      *(float4*)&WqS[row][c4] = *(const float4*)(Wq + (size_t)(c0 + row) * 256 + h * 32 + c4);
      *(float4*)&WkS[row][c4] = *(const float4*)(Wk + (size_t)(d0 + row) * 256 + h * 32 + c4);
    }
    __syncthreads();
    int jo = (tid >> 4) * 4, io = (tid & 15) * 4;
    float acc[4][4];
#pragma unroll
    for (int j = 0; j < 4; j++)
#pragma unroll
      for (int i = 0; i < 4; i++) acc[j][i] = 0.f;
#pragma unroll
    for (int t = 0; t < 32; t++){
#pragma unroll
      for (int j = 0; j < 4; j++){
        float kv = WkS[jo + j][t];
#pragma unroll
        for (int i = 0; i < 4; i++) acc[j][i] = fmaf(kv, WqS[io + i][t], acc[j][i]);
      }
    }
#pragma unroll
    for (int j = 0; j < 4; j++){
      uint2 o;
      o.x = pk2(acc[j][0] * QSCALE, acc[j][1] * QSCALE);
      o.y = pk2(acc[j][2] * QSCALE, acc[j][3] * QSCALE);
      *(uint2*)(Mt + (size_t)(hd0 + jo + j) * 256 + c0 + io) = o;
    }
    if (c0 == 0 && tid < 64){
      float s = 0.f;
#pragma unroll
      for (int t = 0; t < 32; t++) s = fmaf(WkS[tid][t], bq[h * 32 + t], s);
      pb[hd0 + tid] = s * QSCALE;
    }
    return;
  }
  if (bid < 384){
    int t0 = bid - 256;
    int hd0 = (t0 & 31) * 64, n0 = (t0 >> 5) * 64;
    int h = hd0 >> 8, d0 = hd0 & 255;
    float (*WvS)[33] = (float(*)[33])smem;
    float (*WoS)[65] = (float(*)[65])(smem + 64 * 33);
#pragma unroll
    for (int s = 0; s < 2; s++){
      int idx = tid + s * 256;
      int row = idx >> 3, c4 = (idx & 7) * 4;
      *(float4*)&WvS[row][c4] = *(const float4*)(Wv + (size_t)(d0 + row) * 256 + h * 32 + c4);
      int row2 = idx >> 4, c42 = (idx & 15) * 4;
      *(float4*)&WoS[row2][c42] = *(const float4*)(Wo + (size_t)(h * 32 + row2) * 256 + n0 + c42);
    }
    __syncthreads();
    int jo = (tid >> 4) * 4, io = (tid & 15) * 4;
    float acc[4][4];
#pragma unroll
    for (int i = 0; i < 4; i++)
#pragma unroll
      for (int j = 0; j < 4; j++) acc[i][j] = 0.f;
#pragma unroll
    for (int t = 0; t < 32; t++){
#pragma unroll
      for (int i = 0; i < 4; i++){
        float ov = WoS[t][io + i];
#pragma unroll
        for (int j = 0; j < 4; j++) acc[i][j] = fmaf(ov, WvS[jo + j][t], acc[i][j]);
      }
    }
#pragma unroll
    for (int i = 0; i < 4; i++){
      uint2 o;
      o.x = pk2(acc[i][0], acc[i][1]);
      o.y = pk2(acc[i][2], acc[i][3]);
      *(uint2*)(Gt + (size_t)(n0 + io + i) * 2048 + hd0 + jo) = o;
    }
    return;
  }
  if (bid == 384){
    int n = tid;
    float s = bo[n];
    for (int j = 0; j < 256; j++) s = fmaf(bv[j], Wo[(size_t)j * 256 + n], s);
    bo2[n] = s;
    return;
  }
  if (bid < 641){
    int* df = (int*)smem;
    if (tid == 0) df[0] = 0;
    __syncthreads();
    int idx = (bid - 385) * 256 + tid;
    unsigned int v = maskw[idx];
    int bits = 0;
    if (v == 0x3F800000u) bits = 2;
    else if (v & 0xFFFFFF00u) bits = 1;
    int b2 = __any(bits & 2) ? 2 : 0;
    int b1 = __any(bits & 1) ? 1 : 0;
    if ((tid & 63) == 0 && (b1 | b2)) atomicOr(df, b1 | b2);
    __syncthreads();
    if (tid == 0) flagsArr[bid - 385] = df[0];
    return;
  }
  {
    int gid = (bid - 641) * 256 + tid;
    int b = gid >> 6, c = gid & 63;
    float4 v = ((const float4*)(emb + (size_t)batch[b] * D))[c];
    ((float4*)(X + (size_t)b * D))[c] = v;
    uint2 p;
    p.x = pk2(v.x, v.y);
    p.y = pk2(v.z, v.w);
    ((uint2*)Xb)[gid] = p;
  }
}

// ---------------- bf16 MFMA GEMM (direct staging) + XCD swizzle ----------------
template<int BM, int BN, int EPI, bool OUTBF>
__global__ __launch_bounds__(256) void k_mgemm(const unsigned short* __restrict__ A,
                                               const unsigned short* __restrict__ Bt,
                                               const float* __restrict__ bias,
                                               void* __restrict__ Cout,
                                               int M, int N, int K){
  constexpr int BK = 64;
  constexpr int WM = BM / 2, WN = BN / 2;
  constexpr int MR = WM / 16, NR = WN / 16;
  constexpr int AIT = BM * 8 / 256;
  constexpr int BIT = BN * 8 / 256;
  __shared__ __align__(16) unsigned short As[BM * BK];
  __shared__ __align__(16) unsigned short Bs[BN * BK];
  char* ab = (char*)As; char* bb = (char*)Bs;
  const int tid = threadIdx.x;
  const int w = tid >> 6, lane = tid & 63;
  const int wm = w >> 1, wn = w & 1;
  const int gx = gridDim.x;
  const int nwg = gx * gridDim.y;
  const int o = blockIdx.y * gx + blockIdx.x;
  const int lin = (o & 7) * (nwg >> 3) + (o >> 3);
  const int row0 = (lin / gx) * BM, col0 = (lin % gx) * BN;
  f32x4 acc[MR][NR];
#pragma unroll
  for (int m = 0; m < MR; m++)
#pragma unroll
    for (int n = 0; n < NR; n++) acc[m][n] = (f32x4){0.f, 0.f, 0.f, 0.f};

  for (int k0 = 0; k0 < K; k0 += BK){
#pragma unroll
    for (int s = 0; s < AIT; s++){
      int c = s * 256 + tid;
      int r = c >> 3, jj = c & 7;
      uint4 v = *(const uint4*)(A + (size_t)(row0 + r) * K + k0 + jj * 8);
      *(uint4*)(ab + ESWZ(r, r * 128 + jj * 16)) = v;
    }
#pragma unroll
    for (int s = 0; s < BIT; s++){
      int c = s * 256 + tid;
      int r = c >> 3, jj = c & 7;
      uint4 v = *(const uint4*)(Bt + (size_t)(col0 + r) * K + k0 + jj * 8);
      *(uint4*)(bb + ESWZ(r, r * 128 + jj * 16)) = v;
    }
    __syncthreads();
#pragma unroll
    for (int kk = 0; kk < 2; kk++){
      short8 af[MR], bf[NR];
#pragma unroll
      for (int m = 0; m < MR; m++){
        int r = wm * WM + m * 16 + (lane & 15);
        af[m] = *(const short8*)(ab + ESWZ(r, r * 128 + (kk * 4 + (lane >> 4)) * 16));
      }
#pragma unroll
      for (int n = 0; n < NR; n++){
        int r = wn * WN + n * 16 + (lane & 15);
        bf[n] = *(const short8*)(bb + ESWZ(r, r * 128 + (kk * 4 + (lane >> 4)) * 16));
      }
#pragma unroll
      for (int m = 0; m < MR; m++)
#pragma unroll
        for (int n = 0; n < NR; n++)
          acc[m][n] = __builtin_amdgcn_mfma_f32_16x16x32_bf16(af[m], bf[n], acc[m][n], 0, 0, 0);
    }
    __syncthreads();
  }
#pragma unroll
  for (int m = 0; m < MR; m++){
#pragma unroll
    for (int n = 0; n < NR; n++){
      int col = col0 + wn * WN + n * 16 + (lane & 15);
      float bsv = bias[col];
      int rbase = row0 + wm * WM + m * 16 + (lane >> 4) * 4;
#pragma unroll
      for (int r = 0; r < 4; r++){
        float v = acc[m][n][r] + bsv;
        if (EPI == 3) v = fmaxf(v, 0.f);
        if (OUTBF) ((unsigned short*)Cout)[(size_t)(rbase + r) * N + col] = f2bf(v);
        else       ((float*)Cout)[(size_t)(rbase + r) * N + col] = v;
      }
    }
  }
}

// ---------------- attention core: 23.3 KB LDS, split-K scores (gather-BW ceiling) ----------------
__global__ __launch_bounds__(256) void k_attn(const int* __restrict__ nei_idx,
                                              const void* __restrict__ nei_mask,
                                              const int* __restrict__ flagsArr,
                                              const float* __restrict__ emb,
                                              const unsigned short* __restrict__ Pb,
                                              unsigned short* __restrict__ Cb){
  const int b = blockIdx.x;
  const int tid = threadIdx.x;
  const int w = tid >> 6, lane = tid & 63;
  __shared__ __align__(16) unsigned short EbfH[64 * 128]; // 16 KB: E k-half tile / PV partials
  __shared__ __align__(16) unsigned short Pl[9 * 256];    // 4.5 KB, row 8 = zeros
  __shared__ float sc[NH * LN_];
  __shared__ float mskv[LN_];
  __shared__ int   fred[4];
  char* eb = (char*)EbfH;
  char* pl = (char*)Pl;
  unsigned* pfu = (unsigned*)EbfH;

  {
    int f = flagsArr[tid];
#pragma unroll
    for (int off = 32; off; off >>= 1) f |= __shfl_xor(f, off, 64);
    if (lane == 0) fred[w] = f;
  }
  float4 vr[16];
#pragma unroll
  for (int i = 0; i < 16; i++){
    int nid = nei_idx[(size_t)b * LN_ + w * 16 + i];
    vr[i] = ((const float4*)(emb + (size_t)nid * D))[lane];
  }
  {
    int r = tid >> 5, cb16 = (tid & 31) * 16;
    uint4 v = *(const uint4*)((const char*)Pb + (size_t)b * 4096 + r * 512 + cb16);
    *(uint4*)(pl + ESWZ(r, r * 512 + cb16)) = v;
  }
  if (tid < 64) *(uint2*)(pl + 8 * 512 + tid * 8) = make_uint2(0u, 0u);
  __syncthreads();

  if (tid < LN_){
    int fl = fred[0] | fred[1] | fred[2] | fred[3];
    int mf = (fl & 2) ? 2 : ((fl & 1) ? 1 : 0);
    bool m;
    if (mf == 1)      m = ((const unsigned char*)nei_mask)[(size_t)b * LN_ + tid] != 0;
    else if (mf == 2) m = ((const float*)nei_mask)[(size_t)b * LN_ + tid] != 0.f;
    else              m = ((const int*)nei_mask)[(size_t)b * LN_ + tid] != 0;
    mskv[tid] = m ? 1.f : 0.f;
  }

  f32x4 acc = {0.f, 0.f, 0.f, 0.f};
  const int hr = lane & 15;
  const int arow = hr < 8 ? hr : 8;
  const int bl = w * 16 + (lane & 15);
  const int koff = (lane >> 4) * 16;
#pragma unroll
  for (int half = 0; half < 2; half++){
    if ((lane >> 5) == half){
      int cl = lane & 31;
#pragma unroll
      for (int i = 0; i < 16; i++){
        int l = w * 16 + i;
        uint2 p;
        p.x = pk2(vr[i].x, vr[i].y);
        p.y = pk2(vr[i].z, vr[i].w);
        *(uint2*)(eb + ESWZ(l, l * 256 + cl * 8)) = p;
      }
    }
    __syncthreads();
    __builtin_amdgcn_s_setprio(1);
#pragma unroll
    for (int kk = 0; kk < 4; kk++){
      int kabs = half * 4 + kk;
      short8 af = *(const short8*)(pl + ESWZ(arow, arow * 512 + kabs * 64 + koff));
      short8 bf = *(const short8*)(eb + ESWZ(bl, bl * 256 + kk * 64 + koff));
      acc = __builtin_amdgcn_mfma_f32_16x16x32_bf16(af, bf, acc, 0, 0, 0);
    }
    __builtin_amdgcn_s_setprio(0);
    __syncthreads();
  }
  {
    int hb = (lane >> 4) * 4;
    if (hb < 8){
#pragma unroll
      for (int r = 0; r < 4; r++) sc[(hb + r) * LN_ + bl] = acc[r];
    }
  }
  __syncthreads();

  {
    int h = tid >> 5, j = tid & 31;
    float v0 = mskv[j]      > 0.5f ? -INFINITY : sc[h * LN_ + j];
    float v1 = mskv[j + 32] > 0.5f ? -INFINITY : sc[h * LN_ + j + 32];
    float m = fmaxf(v0, v1);
#pragma unroll
    for (int off = 16; off; off >>= 1) m = fmaxf(m, __shfl_xor(m, off, 64));
    float e0 = __expf(v0 - m), e1 = __expf(v1 - m);
    float s = e0 + e1;
#pragma unroll
    for (int off = 16; off; off >>= 1) s += __shfl_xor(s, off, 64);
    float inv = 1.f / s;
    sc[h * LN_ + j]      = e0 * inv;
    sc[h * LN_ + j + 32] = e1 * inv;
  }
  __syncthreads();

  {
    float4 pacc[NH];
#pragma unroll
    for (int h = 0; h < NH; h++) pacc[h] = make_float4(0.f, 0.f, 0.f, 0.f);
#pragma unroll
    for (int i = 0; i < 16; i++){
      int l = w * 16 + i;
#pragma unroll
      for (int h = 0; h < NH; h++){
        float t = sc[h * LN_ + l];
        pacc[h].x = fmaf(t, vr[i].x, pacc[h].x);
        pacc[h].y = fmaf(t, vr[i].y, pacc[h].y);
        pacc[h].z = fmaf(t, vr[i].z, pacc[h].z);
        pacc[h].w = fmaf(t, vr[i].w, pacc[h].w);
      }
    }
#pragma unroll
    for (int h = 0; h < NH; h++){
      uint2 p;
      p.x = pk2(pacc[h].x, pacc[h].y);
      p.y = pk2(pacc[h].z, pacc[h].w);
      *(uint2*)&pfu[w * 1024 + h * 128 + lane * 2] = p;
    }
  }
  __syncthreads();

#pragma unroll
  for (int s = 0; s < 2; s++){
    int gi = tid + s * 256;
    int h = gi >> 6, d4 = gi & 63;
    float x = 0.f, y = 0.f, z = 0.f, u = 0.f;
#pragma unroll
    for (int wv = 0; wv < 4; wv++){
      uint2 p = *(uint2*)&pfu[wv * 1024 + h * 128 + d4 * 2];
      x += bflo(p.x); y += bfhi(p.x);
      z += bflo(p.y); u += bfhi(p.y);
    }
    uint2 o;
    o.x = pk2(x, y);
    o.y = pk2(z, u);
    *(uint2*)(Cb + (size_t)b * 2048 + h * 256 + d4 * 4) = o;
  }
}

// ---------------- LayerNorm(out = LN(A+B)), optional bf16 copy ----------------
__global__ __launch_bounds__(256) void k_ln(const float* __restrict__ A,
                                            const float* __restrict__ Bv,
                                            const float* __restrict__ w,
                                            const float* __restrict__ bi,
                                            float* __restrict__ out,
                                            unsigned short* __restrict__ outb){
  const int row = blockIdx.x, tid = threadIdx.x;
  const int wv = tid >> 6, lane = tid & 63;
  __shared__ float red[8];
  float v = A[(size_t)row * D + tid] + Bv[(size_t)row * D + tid];
  float s = wave_sum(v);
  if (lane == 0) red[wv] = s;
  __syncthreads();
  float mu = (red[0] + red[1] + red[2] + red[3]) * (1.f / D);
  float d = v - mu;
  float s2 = wave_sum(d * d);
  if (lane == 0) red[4 + wv] = s2;
  __syncthreads();
  float var = (red[4] + red[5] + red[6] + red[7]) * (1.f / D);
  float res = d * rsqrtf(var + EPSV) * w[tid] + bi[tid];
  out[(size_t)row * D + tid] = res;
  if (outb) outb[(size_t)row * D + tid] = f2bf(res);
}

// ---------------- launch ----------------
extern "C" void kernel_launch(void* const* d_in, const int* in_sizes, int n_in,
                              void* d_out, int out_size, void* d_ws, size_t ws_size,
                              hipStream_t stream){
  (void)in_sizes; (void)n_in; (void)out_size; (void)ws_size;
  const int*   batch    = (const int*)d_in[0];
  const int*   nei_idx  = (const int*)d_in[1];
  const void*  nei_mask = d_in[2];
  const float* emb      = (const float*)d_in[3];
  const float* Wq = (const float*)d_in[4];  const float* bq = (const float*)d_in[5];
  const float* Wk = (const float*)d_in[6];  /* bk dropped: softmax-invariant */
  const float* Wv = (const float*)d_in[8];  const float* bv = (const float*)d_in[9];
  const float* Wo = (const float*)d_in[10]; const float* bo = (const float*)d_in[11];
  const float* W1 = (const float*)d_in[12]; const float* b1 = (const float*)d_in[13];
  const float* W2 = (const float*)d_in[14]; const float* b2 = (const float*)d_in[15];
  const float* ln1w = (const float*)d_in[16]; const float* ln1b = (const float*)d_in[17];
  const float* ln2w = (const float*)d_in[18]; const float* ln2b = (const float*)d_in[19];

  float* ws = (float*)d_ws;
  // 4-MiB slots
  float* X  = ws;                        // slot 0
  float* Y  = ws + (size_t)1 * 1048576;  // slot 1
  float* S  = ws + (size_t)2 * 1048576;  // slot 2
  float* F  = ws + (size_t)3 * 1048576;  // slot 3
  unsigned short* Pbf = (unsigned short*)(ws + (size_t)4 * 1048576);  // slots 4-7 [4096][2048]
  unsigned short* Cb  = Pbf;             // alias: attn block b reads P[b] fully before writing C[b]
  unsigned short* Sb  = (unsigned short*)(ws + (size_t)8 * 1048576);  // slot 8
  unsigned short* HHb = (unsigned short*)(ws + (size_t)9 * 1048576);  // slots 9-10
  unsigned short* Xb  = (unsigned short*)(ws + (size_t)11 * 1048576); // slot 11
  char* wb = (char*)(ws + (size_t)12 * 1048576);
  unsigned short* W1t = (unsigned short*)(wb);                        // 512 KiB
  unsigned short* W2t = (unsigned short*)(wb + (512u << 10));         // 512 KiB
  unsigned short* Mt  = (unsigned short*)(wb + (1024u << 10));        // 1 MiB
  unsigned short* Gt  = (unsigned short*)(wb + (2048u << 10));        // 1 MiB
  float* pbv  = (float*)(wb + (3072u << 10));                         // 8 KiB
  float* bo2  = (float*)(wb + (3072u << 10) + 8192);                  // 1 KiB
  int*   flagsArr = (int*)(wb + (3072u << 10) + 16384);               // 256 ints
  float* out = (float*)d_out;

  k_prep<<<1665, 256, 0, stream>>>(Wq, Wk, Wv, Wo, W1, W2, bq, bv, bo,
                                   batch, emb, (const unsigned int*)nei_mask,
                                   W1t, W2t, Mt, Gt, pbv, bo2, X, Xb, flagsArr);
  // P = Xb @ Mt^T + pb  [bf16 out], N=2048
  k_mgemm<128, 64, 2, true><<<dim3(2048 / 64, BQ / 128), 256, 0, stream>>>(Xb, Mt, pbv, Pbf, BQ, 2048, 256);
  k_attn<<<BQ, 256, 0, stream>>>(nei_idx, nei_mask, flagsArr, emb, Pbf, Cb);
  // Y = Cb @ Gt^T + bo2  [f32 out], K=2048
  k_mgemm<32, 64, 2, false><<<dim3(D / 64, BQ / 32), 256, 0, stream>>>(Cb, Gt, bo2, Y, BQ, D, 2048);
  k_ln<<<BQ, 256, 0, stream>>>(X, Y, ln1w, ln1b, S, Sb);
  // HH = relu(S@W1 + b1)  [bf16 out]
  k_mgemm<128, 64, 3, true><<<dim3(DFF / 64, BQ / 128), 256, 0, stream>>>(Sb, W1t, b1, HHb, BQ, DFF, 256);
  // F = relu(HH@W2 + b2)  [f32 out]
  k_mgemm<32, 64, 3, false><<<dim3(D / 64, BQ / 32), 256, 0, stream>>>(HHb, W2t, b2, F, BQ, D, DFF);
  k_ln<<<BQ, 256, 0, stream>>>(S, F, ln2w, ln2b, out, nullptr);
}